// Round 8
// baseline (350.215 us; speedup 1.0000x reference)
//
#include <hip/hip_runtime.h>

// Guided filter r=3 (7x7 box, zero-pad /49), fused streaming kernel. R14.
// Ledger invariant R8-R13: ~1000 CU-cyc per 128-col block-row across ALL
// structures; no pipe saturated; ~4.8 waves/CU measured everywhere.
// => per-row serial chain (~2 LDS round trips + VALU + load waits) with
// ~1.2 waves/SIMD of effective overlap. R14 is the decisive TLP test:
// cheapest-possible rows, 4x the wave supply.
//   - C=1 (thread = 1 column), TPB=64, OUTW=52, SEGH=32:
//     grid 20x32x8 = 5120 blocks = 20/CU schedulable.
//   - SINGLE-slot LDS (same-row produce->consume, same-wave in-order):
//     4 arrays x 70 = 3920 B/block -> LDS allows 40 blocks/CU.
//   - __launch_bounds__(64,4): VGPR cap 128 (state ~84 floats + temps).
//   - Warm-up gating: phB only r>=5, phD only r>=12 (ring algebra: early
//     ab entries are added and subtracted before first output).
//   - Single instantiation, modest unroll (R13's I$-bloat lesson).
//
// Thread = image column x = s*52 - 6 + t. Outputs t in [6,57] (52 cols).
// ab valid for t in [3,60]; outputs read ab t-3..t+3 in [3,60] -- never
// touch edge-garbage ab. Guards (LDS idx 0..2, 67..69) stay zero.
// Sweep 44 rows r=0..43: entering y=Yb+r, ab row yc=y-3, output o=y-6.
// Vertical sums: rolling register colsums; leaving ab from depth-8 reg
// ring (slot=r&7, static); leaving I from I-ring; leaving p0..p2 from
// global reload (1-row lead, L2-resident); Io from I-ring.

typedef float v4 __attribute__((ext_vector_type(4)));
typedef float v2 __attribute__((ext_vector_type(2)));

#define TPB   64
#define OUTW  52
#define SEGH  32
#define HW    1024
#define NIDX  70           // 64 data + 3 guard each side
#define EPSF  1e-6f
#define INV49 (1.0f/49.0f)

struct St {
    v4 s14, s58;               // stage-1 colsums (I,II,p0,p1),(p2,q0,q1,q2)
    v4 t64; v2 t62;            // stage-2 colsums (a0,b0,a1,b1),(a2,b2)
    v4 rab4[8]; v2 rab2[8];    // ab ring, slot = r&7 (static via template)
    float rI[8];               // I ring, slot = r&7
    v4 ent[2];                 // entering rows, ping-pong [r&1]
    float lvp0, lvp1, lvp2;    // leaving p0..p2 (this row)
    float lvn0, lvn1, lvn2;    // next row's leaving (1-row lead)
};

template<int U>
__device__ __forceinline__ void rowStep(
    St& S, const int r, const int Yb, const int t, const int xc,
    const bool ok, const bool sok, const int x,
    const float* __restrict__ Ip, const float* __restrict__ P0,
    const float* __restrict__ P1, const float* __restrict__ P2,
    float* __restrict__ Q0, float* __restrict__ Q1, float* __restrict__ Q2,
    v4* __restrict__ c8A, v4* __restrict__ c8B,
    v4* __restrict__ c6A, v2* __restrict__ c6B)
{
    constexpr int WS  = U;            // ring write slot (r&7 == U)
    constexpr int LS  = (U + 1) & 7;  // leaving slot (row r-7)
    constexpr int IOS = (U + 2) & 7;  // Io slot (row r-6)

    // ---- A: stage-1 vertical colsum update (enter y, leave y-7) -> cs8
    {
        const v4 E = S.ent[U & 1];
        const float LI = S.rI[LS];
        v4 d14, d58;
        d14.x = E.x - LI;
        d14.y = E.x*E.x - LI*LI;
        d14.z = E.y - S.lvp0;
        d14.w = E.z - S.lvp1;
        d58.x = E.w - S.lvp2;
        d58.y = E.x*E.y - LI*S.lvp0;
        d58.z = E.x*E.z - LI*S.lvp1;
        d58.w = E.x*E.w - LI*S.lvp2;
        S.s14 += d14; S.s58 += d58;
        c8A[t+3] = S.s14;
        c8B[t+3] = S.s58;
        S.rI[WS] = E.x;
    }
    asm volatile("" ::: "memory");

    // ---- B: stage-1 horizontal 7-tap -> ab -> ring -> stage-2 colsums
    if (r >= 5) {
        const v4 A = ((c8A[t+0] + c8A[t+1]) + (c8A[t+2] + c8A[t+3]))
                   + ((c8A[t+4] + c8A[t+5]) + c8A[t+6]);
        const v4 B = ((c8B[t+0] + c8B[t+1]) + (c8B[t+2] + c8B[t+3]))
                   + ((c8B[t+4] + c8B[t+5]) + c8B[t+6]);
        const int  yc   = Yb + r - 3;
        const bool abok = ok && ((unsigned)yc < HW);
        const float mi  = A.x * INV49;
        const float mii = A.y * INV49;
        const float rv  = __builtin_amdgcn_rcpf(mii - mi*mi + EPSF);
        const float mp0 = A.z*INV49, mp1 = A.w*INV49, mp2 = B.x*INV49;
        const float a0 = (B.y*INV49 - mi*mp0)*rv;
        const float a1 = (B.z*INV49 - mi*mp1)*rv;
        const float a2 = (B.w*INV49 - mi*mp2)*rv;
        const float b0 = fmaf(-a0, mi, mp0);
        const float b1 = fmaf(-a1, mi, mp1);
        const float b2 = fmaf(-a2, mi, mp2);
        v4 ab4; v2 ab2;
        ab4.x = abok?a0:0.f; ab4.y = abok?b0:0.f;
        ab4.z = abok?a1:0.f; ab4.w = abok?b1:0.f;
        ab2.x = abok?a2:0.f; ab2.y = abok?b2:0.f;
        S.t64 += ab4 - S.rab4[LS];  S.rab4[WS] = ab4;
        S.t62 += ab2 - S.rab2[LS];  S.rab2[WS] = ab2;
        c6A[t+3] = S.t64;
        c6B[t+3] = S.t62;
    }
    asm volatile("" ::: "memory");

    // ---- C: prefetch. Entering row r+2 (HBM, 2-row lead); leaving
    //         p0..p2 for row r+1 (L2, 1-row lead). Uniform-y branches.
    if (r <= 41) {
        const int yE = Yb + r + 2;
        if ((unsigned)yE < HW) {
            const size_t ro = (size_t)yE*HW + xc;
            const float vI = Ip[ro], va = P0[ro], vb = P1[ro], vc = P2[ro];
            v4 E;
            E.x = ok?vI:0.f; E.y = ok?va:0.f; E.z = ok?vb:0.f; E.w = ok?vc:0.f;
            S.ent[U & 1] = E;
        } else {
            const v4 z = {0.f,0.f,0.f,0.f};
            S.ent[U & 1] = z;
        }
    }
    if (r <= 42) {
        const int yL = Yb + r - 6;        // = Yb + (r+1) - 7
        if (r + 1 >= 7 && (unsigned)yL < HW) {
            const size_t ro = (size_t)yL*HW + xc;
            const float va = P0[ro], vb = P1[ro], vc = P2[ro];
            S.lvn0 = ok?va:0.f; S.lvn1 = ok?vb:0.f; S.lvn2 = ok?vc:0.f;
        } else {
            S.lvn0 = 0.f; S.lvn1 = 0.f; S.lvn2 = 0.f;
        }
    }

    // ---- D: stage-2 horizontal 7-tap -> output row o = y-6
    if (r >= 12) {
        const v4 A6 = ((c6A[t+0] + c6A[t+1]) + (c6A[t+2] + c6A[t+3]))
                    + ((c6A[t+4] + c6A[t+5]) + c6A[t+6]);
        const v2 B6 = ((c6B[t+0] + c6B[t+1]) + (c6B[t+2] + c6B[t+3]))
                    + ((c6B[t+4] + c6B[t+5]) + c6B[t+6]);
        if (sok) {
            const float io = S.rI[IOS];   // I at output row (ring, r-6)
            const int o = Yb + r - 6;
            const size_t ob = (size_t)o * HW + x;
            float q;
            q = fminf(fmaxf(fmaf(A6.x*INV49, io, A6.y*INV49), 0.f), 1.f);
            Q0[ob] = q;
            q = fminf(fmaxf(fmaf(A6.z*INV49, io, A6.w*INV49), 0.f), 1.f);
            Q1[ob] = q;
            q = fminf(fmaxf(fmaf(B6.x*INV49, io, B6.y*INV49), 0.f), 1.f);
            Q2[ob] = q;
        }
    }
    S.lvp0 = S.lvn0; S.lvp1 = S.lvn1; S.lvp2 = S.lvn2;
}

__global__ __launch_bounds__(TPB, 4) void gf_kernel(
    const float* __restrict__ I, const float* __restrict__ P,
    float* __restrict__ Q)
{
    // single-slot colsum rows (same-row produce->consume, 1 wave)
    __shared__ v4 c8A[NIDX];   // 1120 B: sI,sII,sp0,sp1
    __shared__ v4 c8B[NIDX];   // 1120 B: sp2,sq0,sq1,sq2
    __shared__ v4 c6A[NIDX];   // 1120 B: ta0,tb0,ta1,tb1
    __shared__ v2 c6B[NIDX];   //  560 B: ta2,tb2      -> 3920 B total

    const int s   = blockIdx.x;      // x-stripe (20)
    const int seg = blockIdx.y;      // y-segment (32)
    const int b   = blockIdx.z;      // batch (8)
    const int t   = threadIdx.x;

    const int Yb = seg*SEGH - 6;
    const int x  = s*OUTW - 6 + t;
    const bool ok = (unsigned)x < HW;
    const int  xc = min(max(x, 0), HW-1);
    const bool sok = (t >= 6) && (t <= 57) && ok;

    const float* Ip = I + (size_t)b*HW*HW;
    const float* P0 = P + ((size_t)b*3 + 0)*HW*HW;
    const float* P1 = P + ((size_t)b*3 + 1)*HW*HW;
    const float* P2 = P + ((size_t)b*3 + 2)*HW*HW;
    float* Q0 = Q + ((size_t)b*3 + 0)*HW*HW;
    float* Q1 = Q + ((size_t)b*3 + 1)*HW*HW;
    float* Q2 = Q + ((size_t)b*3 + 2)*HW*HW;

    // zero-init LDS (guard cells idx 0..2, 67..69 must read as 0)
    {
        const v4 z4 = {0.f,0.f,0.f,0.f};
        const v2 z2 = {0.f,0.f};
        for (int i = t; i < NIDX; i += TPB) {
            c8A[i] = z4; c8B[i] = z4; c6A[i] = z4; c6B[i] = z2;
        }
    }

    St S;
    {
        const v4 z4 = {0.f,0.f,0.f,0.f};
        const v2 z2 = {0.f,0.f};
        S.s14 = z4; S.s58 = z4; S.t64 = z4; S.t62 = z2;
        #pragma unroll
        for (int i = 0; i < 8; ++i) {
            S.rab4[i] = z4; S.rab2[i] = z2; S.rI[i] = 0.f;
        }
        S.lvp0=S.lvp1=S.lvp2=0.f; S.lvn0=S.lvn1=S.lvn2=0.f;
        // prologue: entering rows 0,1
        #pragma unroll
        for (int q = 0; q < 2; ++q) {
            const int yE = Yb + q;
            if ((unsigned)yE < HW) {
                const size_t ro = (size_t)yE*HW + xc;
                const float vI = Ip[ro], va = P0[ro], vb = P1[ro], vc = P2[ro];
                v4 E;
                E.x = ok?vI:0.f; E.y = ok?va:0.f; E.z = ok?vb:0.f; E.w = ok?vc:0.f;
                S.ent[q] = E;
            } else {
                S.ent[q] = z4;
            }
        }
    }
    __syncthreads();   // LDS zero-init visible (single wave: cheap)

    // 44 rows: r = 0..43 (ring slot r&7 == U by construction)
    for (int m = 0; m < 5; ++m) {
        const int r0 = m*8;
        rowStep<0>(S, r0+0, Yb, t, xc, ok, sok, x, Ip,P0,P1,P2, Q0,Q1,Q2, c8A,c8B,c6A,c6B);
        rowStep<1>(S, r0+1, Yb, t, xc, ok, sok, x, Ip,P0,P1,P2, Q0,Q1,Q2, c8A,c8B,c6A,c6B);
        rowStep<2>(S, r0+2, Yb, t, xc, ok, sok, x, Ip,P0,P1,P2, Q0,Q1,Q2, c8A,c8B,c6A,c6B);
        rowStep<3>(S, r0+3, Yb, t, xc, ok, sok, x, Ip,P0,P1,P2, Q0,Q1,Q2, c8A,c8B,c6A,c6B);
        rowStep<4>(S, r0+4, Yb, t, xc, ok, sok, x, Ip,P0,P1,P2, Q0,Q1,Q2, c8A,c8B,c6A,c6B);
        rowStep<5>(S, r0+5, Yb, t, xc, ok, sok, x, Ip,P0,P1,P2, Q0,Q1,Q2, c8A,c8B,c6A,c6B);
        rowStep<6>(S, r0+6, Yb, t, xc, ok, sok, x, Ip,P0,P1,P2, Q0,Q1,Q2, c8A,c8B,c6A,c6B);
        rowStep<7>(S, r0+7, Yb, t, xc, ok, sok, x, Ip,P0,P1,P2, Q0,Q1,Q2, c8A,c8B,c6A,c6B);
    }
    // tail rows 40..43 (40 % 8 == 0, slots line up)
    rowStep<0>(S, 40, Yb, t, xc, ok, sok, x, Ip,P0,P1,P2, Q0,Q1,Q2, c8A,c8B,c6A,c6B);
    rowStep<1>(S, 41, Yb, t, xc, ok, sok, x, Ip,P0,P1,P2, Q0,Q1,Q2, c8A,c8B,c6A,c6B);
    rowStep<2>(S, 42, Yb, t, xc, ok, sok, x, Ip,P0,P1,P2, Q0,Q1,Q2, c8A,c8B,c6A,c6B);
    rowStep<3>(S, 43, Yb, t, xc, ok, sok, x, Ip,P0,P1,P2, Q0,Q1,Q2, c8A,c8B,c6A,c6B);
}

extern "C" void kernel_launch(void* const* d_in, const int* in_sizes, int n_in,
                              void* d_out, int out_size, void* d_ws, size_t ws_size,
                              hipStream_t stream) {
    const float* I = (const float*)d_in[0];
    const float* P = (const float*)d_in[1];
    // d_in[2] = radius (always 3; hardcoded)
    float* Q = (float*)d_out;

    dim3 grid(20, 32, 8);   // x-stripes (20x52=1040), y-segments, batch
    gf_kernel<<<grid, TPB, 0, stream>>>(I, P, Q);
}